// Round 1
// 236.535 us; speedup vs baseline: 1.0401x; 1.0401x over previous
//
#include <hip/hip_runtime.h>

#define NXD 4096
#define NYD 4096

typedef float f32x4 __attribute__((ext_vector_type(4)));

// Latency-bound fix: ROWS=2, straight-line, ALL loads (8x float4 rows + 8 edge
// scalars) issued before any use -> ~10-12 outstanding 16B loads per wave
// instead of the rolling window's 2-4. Keep VGPR <= 64 so occupancy stays
// 8 waves/SIMD (32/CU): in-flight bytes/CU ~5KB -> Little's law ~6 TB/s.
__global__ __launch_bounds__(256) void DiffReactParamPDE_85478439125433_kernel(
    const float* __restrict__ state,
    const float* __restrict__ bc,
    const float* __restrict__ a_org,
    const float* __restrict__ b_org,
    const float* __restrict__ k_org,
    float* __restrict__ out)
{
    const float inv_dx2 = 100.0f;

    const int lane = threadIdx.x & 63;
    const int j0 = (blockIdx.x * 256 + threadIdx.x) * 4;  // 4 cols per thread
    const int i0 = blockIdx.y * 2;                        // 2 output rows per thread

    const float* __restrict__ U = state;
    const float* __restrict__ V = state + (size_t)NXD * NYD;
    float* __restrict__ dU = out;
    float* __restrict__ dV = out + (size_t)NXD * NYD;

    // Clamp halo row indices so loads are unconditional (issue back-to-back);
    // boundary values get patched with bc after the loads are in flight.
    const int rT = (i0 == 0) ? 0 : i0 - 1;
    const int rB = (i0 + 2 >= NXD) ? NXD - 1 : i0 + 2;

#define LD4(P, ROW) (*(const float4*)((P) + (size_t)(ROW) * NYD + j0))
    // ---- issue all 8 row loads up front ----
    float4 um = LD4(U, rT);
    float4 u0 = LD4(U, i0);
    float4 u1 = LD4(U, i0 + 1);
    float4 up = LD4(U, rB);
    float4 vm = LD4(V, rT);
    float4 v0 = LD4(V, i0);
    float4 v1 = LD4(V, i0 + 1);
    float4 vp = LD4(V, rB);
#undef LD4

    // bc (1,2,4): [U: L,R,T,B | V: L,R,T,B] -- uniform address -> s_load
    const float uL = bc[0], uR = bc[1], uT = bc[2], uB = bc[3];
    const float vL = bc[4], vR = bc[5], vT = bc[6], vB = bc[7];

    // ---- edge scalars for both compute rows, issued up front ----
    float eLu0 = uL, eLu1 = uL, eLv0 = vL, eLv1 = vL;
    float eRu0 = uR, eRu1 = uR, eRv0 = vR, eRv1 = vR;
    if (lane == 0 && j0 > 0) {
        eLu0 = U[(size_t)i0 * NYD + j0 - 1];
        eLu1 = U[(size_t)(i0 + 1) * NYD + j0 - 1];
        eLv0 = V[(size_t)i0 * NYD + j0 - 1];
        eLv1 = V[(size_t)(i0 + 1) * NYD + j0 - 1];
    }
    if (lane == 63 && j0 + 4 < NYD) {
        eRu0 = U[(size_t)i0 * NYD + j0 + 4];
        eRu1 = U[(size_t)(i0 + 1) * NYD + j0 + 4];
        eRv0 = V[(size_t)i0 * NYD + j0 + 4];
        eRv1 = V[(size_t)(i0 + 1) * NYD + j0 + 4];
    }

    // scalar params (uniform -> scalar pipe, overlaps with vector loads)
    const float a = 0.01f / (1.0f + expf(-a_org[0]));
    const float b = 0.01f / (1.0f + expf(-b_org[0]));
    const float k = 0.01f / (1.0f + expf(-k_org[0]));

    // ---- patch halo rows with bc (block-uniform branches) ----
    if (i0 == 0) {
        um = make_float4(uT, uT, uT, uT);
        vm = make_float4(vT, vT, vT, vT);
    }
    if (i0 + 2 >= NXD) {
        up = make_float4(uB, uB, uB, uB);
        vp = make_float4(vB, vB, vB, vB);
    }

    // =================== row 0 (i0): neighbors um / u1 ===================
    {
        float ulft = __shfl_up(u0.w, 1);   if (lane == 0)  ulft = eLu0;
        float urgt = __shfl_down(u0.x, 1); if (lane == 63) urgt = eRu0;
        float vlft = __shfl_up(v0.w, 1);   if (lane == 0)  vlft = eLv0;
        float vrgt = __shfl_down(v0.x, 1); if (lane == 63) vrgt = eRv0;

        const float lu0 = (um.x + u1.x + ulft + u0.y - 4.0f * u0.x) * inv_dx2;
        const float lu1 = (um.y + u1.y + u0.x + u0.z - 4.0f * u0.y) * inv_dx2;
        const float lu2 = (um.z + u1.z + u0.y + u0.w - 4.0f * u0.z) * inv_dx2;
        const float lu3 = (um.w + u1.w + u0.z + urgt - 4.0f * u0.w) * inv_dx2;

        const float lv0 = (vm.x + v1.x + vlft + v0.y - 4.0f * v0.x) * inv_dx2;
        const float lv1 = (vm.y + v1.y + v0.x + v0.z - 4.0f * v0.y) * inv_dx2;
        const float lv2 = (vm.z + v1.z + v0.y + v0.w - 4.0f * v0.z) * inv_dx2;
        const float lv3 = (vm.w + v1.w + v0.z + vrgt - 4.0f * v0.w) * inv_dx2;

        f32x4 duo, dvo;
        duo.x = a * lu0 + u0.x - u0.x * u0.x * u0.x - v0.x - k;
        duo.y = a * lu1 + u0.y - u0.y * u0.y * u0.y - v0.y - k;
        duo.z = a * lu2 + u0.z - u0.z * u0.z * u0.z - v0.z - k;
        duo.w = a * lu3 + u0.w - u0.w * u0.w * u0.w - v0.w - k;

        dvo.x = b * lv0 + u0.x - v0.x;
        dvo.y = b * lv1 + u0.y - v0.y;
        dvo.z = b * lv2 + u0.z - v0.z;
        dvo.w = b * lv3 + u0.w - v0.w;

        const size_t bo = (size_t)i0 * NYD + j0;
        __builtin_nontemporal_store(duo, (f32x4*)(dU + bo));
        __builtin_nontemporal_store(dvo, (f32x4*)(dV + bo));
    }

    // =================== row 1 (i0+1): neighbors u0 / up ===================
    {
        float ulft = __shfl_up(u1.w, 1);   if (lane == 0)  ulft = eLu1;
        float urgt = __shfl_down(u1.x, 1); if (lane == 63) urgt = eRu1;
        float vlft = __shfl_up(v1.w, 1);   if (lane == 0)  vlft = eLv1;
        float vrgt = __shfl_down(v1.x, 1); if (lane == 63) vrgt = eRv1;

        const float lu0 = (u0.x + up.x + ulft + u1.y - 4.0f * u1.x) * inv_dx2;
        const float lu1 = (u0.y + up.y + u1.x + u1.z - 4.0f * u1.y) * inv_dx2;
        const float lu2 = (u0.z + up.z + u1.y + u1.w - 4.0f * u1.z) * inv_dx2;
        const float lu3 = (u0.w + up.w + u1.z + urgt - 4.0f * u1.w) * inv_dx2;

        const float lv0 = (v0.x + vp.x + vlft + v1.y - 4.0f * v1.x) * inv_dx2;
        const float lv1 = (v0.y + vp.y + v1.x + v1.z - 4.0f * v1.y) * inv_dx2;
        const float lv2 = (v0.z + vp.z + v1.y + v1.w - 4.0f * v1.z) * inv_dx2;
        const float lv3 = (v0.w + vp.w + v1.z + vrgt - 4.0f * v1.w) * inv_dx2;

        f32x4 duo, dvo;
        duo.x = a * lu0 + u1.x - u1.x * u1.x * u1.x - v1.x - k;
        duo.y = a * lu1 + u1.y - u1.y * u1.y * u1.y - v1.y - k;
        duo.z = a * lu2 + u1.z - u1.z * u1.z * u1.z - v1.z - k;
        duo.w = a * lu3 + u1.w - u1.w * u1.w * u1.w - v1.w - k;

        dvo.x = b * lv0 + u1.x - v1.x;
        dvo.y = b * lv1 + u1.y - v1.y;
        dvo.z = b * lv2 + u1.z - v1.z;
        dvo.w = b * lv3 + u1.w - v1.w;

        const size_t bo = (size_t)(i0 + 1) * NYD + j0;
        __builtin_nontemporal_store(duo, (f32x4*)(dU + bo));
        __builtin_nontemporal_store(dvo, (f32x4*)(dV + bo));
    }
}

extern "C" void kernel_launch(void* const* d_in, const int* in_sizes, int n_in,
                              void* d_out, int out_size, void* d_ws, size_t ws_size,
                              hipStream_t stream) {
    const float* state = (const float*)d_in[0];
    const float* bc    = (const float*)d_in[1];
    const float* a_org = (const float*)d_in[2];
    const float* b_org = (const float*)d_in[3];
    const float* k_org = (const float*)d_in[4];
    float* out = (float*)d_out;

    // 256 threads x 4 cols = 1024 cols/block -> 4 x-blocks; 4096/2 y-blocks
    dim3 block(256, 1, 1);
    dim3 grid(NYD / (4 * 256), NXD / 2, 1);
    DiffReactParamPDE_85478439125433_kernel<<<grid, block, 0, stream>>>(
        state, bc, a_org, b_org, k_org, out);
}